// Round 7
// baseline (274.619 us; speedup 1.0000x reference)
//
#include <hip/hip_runtime.h>

#define SEQ    8192
#define S_TILE 244            // valid output positions per 256-pos tile
#define NROW   264            // LDS rows (positions) per chunk
#define CS     2120           // chunk stride in halves (264*8=2112, +8 bank-skew)
#define NTHR   512            // 8 waves; wave owns 2 n-tiles x both m-halves

typedef __attribute__((ext_vector_type(8))) _Float16 half8;
typedef __attribute__((ext_vector_type(4))) _Float16 half4v;
typedef __attribute__((ext_vector_type(4))) float    f32x4;

__device__ __forceinline__ int uni(int v){ return __builtin_amdgcn_readfirstlane(v); }

// Build 'nrec' A-fragment records from raw fp32 weights into LDS.
// Record r2 = tap*2 + mh: lane l holds A[m][k] = W[co=mh*16+(l&15)][ci=(l>>4)*8+j][tap]
// (A-operand layout for mfma_f32_16x16x32: A[m=lane&15][k=quad*8+j]).
// Called inside a barrier interval where 'dst' region's previous contents are dead;
// the next __syncthreads orders it before its consumer layer.
__device__ __forceinline__ void build_recs(const float* __restrict__ W,
                                           int CIN, int K, int nrec,
                                           _Float16* dst, int tid)
{
    for (int idx = tid; idx < nrec * 64; idx += NTHR) {
        int r2 = idx >> 6, lane = idx & 63;
        int tap = r2 >> 1, mh = r2 & 1;
        int co  = mh*16 + (lane & 15);
        int ci0 = (lane >> 4) * 8;
        half8 h;
#pragma unroll
        for (int j = 0; j < 8; ++j) {
            int ci = ci0 + j;
            h[j] = (_Float16)((ci < CIN) ? W[(co*CIN + ci)*K + tap] : 0.0f);
        }
        *(half8*)(dst + r2*512 + lane*8) = h;
    }
}

// ---------------- one conv layer via MFMA ----------------
// in/out: LDS f16, 4 chunks x NROW pos x 8 halves (chunk cb holds ci 8cb..8cb+7).
// B-frag (lane l): pos = base+(l&15)+tap, ci = (l>>4)*8+j -> one b128 at q*CS + pos*8.
// D (C/D layout): col=lane&15 -> pos, row=q*4+r -> co (within m-half).
// rec/bn point into LDS. DOFF: global pos of local 0 = s0+DOFF; outside [0,SEQ)
// forced to 0 (ref zero-pads every layer's input at sequence edges).
template<int K, int DOFF>
__device__ __forceinline__ void conv_layer(
    const _Float16* rec, const float4* bn,
    const _Float16* in, _Float16* outb, int s0, int ntb, int lane)
{
    const int q = lane >> 4, n = lane & 15;
    const _Float16* bbase = in + q*CS + (ntb*16 + n)*8;

    f32x4 acc[2][2];
#pragma unroll
    for (int nt = 0; nt < 2; ++nt)
#pragma unroll
        for (int mh = 0; mh < 2; ++mh) acc[nt][mh] = (f32x4){0.f, 0.f, 0.f, 0.f};

#pragma unroll
    for (int tap = 0; tap < K; ++tap) {
        half8 a0 = *(const half8*)(rec + (tap*2 + 0)*512 + lane*8);
        half8 a1 = *(const half8*)(rec + (tap*2 + 1)*512 + lane*8);
#pragma unroll
        for (int nt = 0; nt < 2; ++nt) {
            half8 bf = *(const half8*)(bbase + nt*128 + tap*8);
            acc[nt][0] = __builtin_amdgcn_mfma_f32_16x16x32_f16(a0, bf, acc[nt][0], 0, 0, 0);
            acc[nt][1] = __builtin_amdgcn_mfma_f32_16x16x32_f16(a1, bf, acc[nt][1], 0, 0, 0);
        }
    }

    // epilogue: relu(acc+bias)*scale+shift, seq-edge zero, pack 4 co -> one b64 LDS write
#pragma unroll
    for (int nt = 0; nt < 2; ++nt) {
        int pos = (ntb + nt)*16 + n;
        bool oob = (unsigned)(s0 + DOFF + pos) >= SEQ;
#pragma unroll
        for (int mh = 0; mh < 2; ++mh) {
            int co0 = mh*16 + q*4;
            half4v hv;
#pragma unroll
            for (int r = 0; r < 4; ++r) {
                float4 p = bn[co0 + r];   // x=scale y=shift z=bias
                float v = fmaxf(acc[nt][mh][r] + p.z, 0.0f)*p.x + p.y;
                if (oob) v = 0.0f;
                hv[r] = (_Float16)v;
            }
            int cb = mh*2 + (q >> 1);
            *(half4v*)(outb + cb*CS + pos*8 + (q & 1)*4) = hv;
        }
    }
}

extern "C" __global__ void __launch_bounds__(NTHR, 4)
dnashape_mfma(const float* __restrict__ x,
    const float* __restrict__ w0, const float* __restrict__ b0, const float* __restrict__ g0,
    const float* __restrict__ bb0, const float* __restrict__ rm0, const float* __restrict__ rv0,
    const float* __restrict__ w1, const float* __restrict__ b1, const float* __restrict__ g1,
    const float* __restrict__ bb1, const float* __restrict__ rm1, const float* __restrict__ rv1,
    const float* __restrict__ w2, const float* __restrict__ b2, const float* __restrict__ g2,
    const float* __restrict__ bb2, const float* __restrict__ rm2, const float* __restrict__ rv2,
    const float* __restrict__ w3, const float* __restrict__ b3, const float* __restrict__ g3,
    const float* __restrict__ bb3, const float* __restrict__ rm3, const float* __restrict__ rv3,
    const float* __restrict__ fw1, const float* __restrict__ fb1,
    const float* __restrict__ fw2, const float* __restrict__ fb2,
    float* __restrict__ out)
{
    // Record regions ping-pong so only two layers' tables are live at once:
    // recA: L0 (6 recs) -> L2 (10) -> MLP (1).  recB: L1 (6) -> L3 (14).
    // Builds are placed in the barrier interval where the region is dead.
    __shared__ _Float16 recA[10*512];   // 10.0 KB
    __shared__ _Float16 recB[14*512];   // 14.0 KB
    __shared__ float4   bnL[128];       //  2.0 KB  (4 layers x 32 co)
    __shared__ _Float16 bufA[4*CS];     // 16.96 KB
    __shared__ _Float16 bufB[4*CS];     // 16.96 KB   total 60544 B -> 2 blocks/CU

    const int tid  = threadIdx.x;
    const int tile = blockIdx.x, b = blockIdx.y;
    const int s0   = tile * S_TILE;

    // Stage input into bufB: chunk0 = f16(x[ci 0..3]) + 4 zeros, chunks 1-3 zero.
    const half8 z8 = {0,0,0,0,0,0,0,0};
    for (int li = tid; li < NROW; li += NTHR) {
        int sg = s0 - 7 + li;   // input origin s0-7 (halo 7)
        bool ok = (unsigned)sg < SEQ;
        float v0 = ok ? x[(b*4 + 0)*SEQ + sg] : 0.f;
        float v1 = ok ? x[(b*4 + 1)*SEQ + sg] : 0.f;
        float v2 = ok ? x[(b*4 + 2)*SEQ + sg] : 0.f;
        float v3 = ok ? x[(b*4 + 3)*SEQ + sg] : 0.f;
        half8 h0 = {(_Float16)v0, (_Float16)v1, (_Float16)v2, (_Float16)v3, 0, 0, 0, 0};
        *(half8*)(bufB + 0*CS + li*8) = h0;
        *(half8*)(bufB + 1*CS + li*8) = z8;
        *(half8*)(bufB + 2*CS + li*8) = z8;
        *(half8*)(bufB + 3*CS + li*8) = z8;
    }
    // Zero bufA halo rows 256..263 (read by later layers, written by none).
    if (tid < 32) *(half8*)(bufA + (tid >> 3)*CS + (256 + (tid & 7))*8) = z8;

    // Build L0/L1 records + folded BN table during staging interval.
    build_recs(w0, 4,  3, 6, recA, tid);
    build_recs(w1, 32, 3, 6, recB, tid);
    if (tid < 128) {
        int l = tid >> 5, co = tid & 31;
        const float *g, *bb, *rm, *rv, *bi;
        if      (l == 0) { g=g0; bb=bb0; rm=rm0; rv=rv0; bi=b0; }
        else if (l == 1) { g=g1; bb=bb1; rm=rm1; rv=rv1; bi=b1; }
        else if (l == 2) { g=g2; bb=bb2; rm=rm2; rv=rv2; bi=b2; }
        else             { g=g3; bb=bb3; rm=rm3; rv=rv3; bi=b3; }
        float scale = g[co] / sqrtf(rv[co] + 1e-5f);
        float shift = bb[co] - rm[co]*scale;
        float4 v; v.x = scale; v.y = shift; v.z = bi[co]; v.w = 0.f;
        bnL[l*32 + co] = v;
    }
    __syncthreads();

    const int lane = tid & 63;
    const int ntb  = uni(tid >> 6) * 2;     // wave-uniform n-tile base

    // Buffer origins: in=s0-7, L0out=s0-6, L1out=s0-5, L2out=s0-3, L3out=s0.
    conv_layer<3, -6>(recA, bnL +  0, bufB, bufA, s0, ntb, lane);
    __syncthreads();
    conv_layer<3, -5>(recB, bnL + 32, bufA, bufB, s0, ntb, lane);
    build_recs(w2, 32, 5, 10, recA, tid);          // recA (L0) dead since last barrier
    __syncthreads();
    conv_layer<5, -3>(recA, bnL + 64, bufB, bufA, s0, ntb, lane);
    build_recs(w3, 32, 7, 14, recB, tid);          // recB (L1) dead
    __syncthreads();
    conv_layer<7,  0>(recB, bnL + 96, bufA, bufB, s0, ntb, lane);
    build_recs(fw1, 32, 1, 1, recA, tid);          // recA (L2) dead; MLP record
    __syncthreads();

    // MLP 32 -> 16 (relu) -> 1: one MFMA per n-tile; D row = h, col = pos.
    {
        const int q = lane >> 4, n = lane & 15;
        half8 am = *(const half8*)(recA + lane*8);
        float fb1v[4], fw2v[4];
#pragma unroll
        for (int r = 0; r < 4; ++r) { fb1v[r] = fb1[q*4 + r]; fw2v[r] = fw2[q*4 + r]; }
        float fb2v = fb2[0];
#pragma unroll
        for (int nt = 0; nt < 2; ++nt) {
            int pos = (ntb + nt)*16 + n;
            half8 bf = *(const half8*)(bufB + q*CS + pos*8);
            f32x4 d = {0.f, 0.f, 0.f, 0.f};
            d = __builtin_amdgcn_mfma_f32_16x16x32_f16(am, bf, d, 0, 0, 0);
            float part = 0.f;
#pragma unroll
            for (int r = 0; r < 4; ++r) part += fmaxf(d[r] + fb1v[r], 0.f)*fw2v[r];
            part += __shfl_xor(part, 16, 64);   // reduce across the 4 quads (h-blocks)
            part += __shfl_xor(part, 32, 64);
            if (lane < 16) {
                int g = s0 + pos;
                if (pos < S_TILE && g < SEQ) out[b*SEQ + g] = part + fb2v;
            }
        }
    }
}

extern "C" void kernel_launch(void* const* d_in, const int* in_sizes, int n_in,
                              void* d_out, int out_size, void* d_ws, size_t ws_size,
                              hipStream_t stream) {
    const float* p[29];
    for (int i = 0; i < 29; ++i) p[i] = (const float*)d_in[i];
    dim3 grid((SEQ + S_TILE - 1) / S_TILE, 128);   // 34 x 128, single dispatch, no d_ws
    dnashape_mfma<<<grid, NTHR, 0, stream>>>(p[0],
        p[1],  p[2],  p[3],  p[4],  p[5],  p[6],
        p[7],  p[8],  p[9],  p[10], p[11], p[12],
        p[13], p[14], p[15], p[16], p[17], p[18],
        p[19], p[20], p[21], p[22], p[23], p[24],
        p[25], p[26], p[27], p[28],
        (float*)d_out);
}

// Round 8
// 173.446 us; speedup vs baseline: 1.5833x; 1.5833x over previous
//
#include <hip/hip_runtime.h>

#define SEQ    8192
#define S_TILE 244            // valid output positions per 256-pos tile
#define NROW   264            // LDS rows (positions) per chunk
#define CS     2120           // chunk stride in halves (264*8=2112, +8 bank-skew)
#define NTHR   256            // 4 waves; wave owns 4 n-tiles x both m-halves
#define NREC   37             // 36 conv A-records + 1 MLP record (each 64 lanes x 16B = 1KB)
#define BN_HALFOFF (NREC*512) // BN region offset (in halves) inside d_ws

typedef __attribute__((ext_vector_type(8))) _Float16 half8;
typedef __attribute__((ext_vector_type(4))) _Float16 half4v;
typedef __attribute__((ext_vector_type(4))) float    f32x4;

__device__ __forceinline__ int uni(int v){ return __builtin_amdgcn_readfirstlane(v); }

// ---------------- prep: weights -> A-fragment-ready f16 records + folded BN ----------------
// One record per block (38 blocks, wide launch). Record (tap, mh): lane l holds
// A[m][k] = W[co=mh*16+(l&15)][ci=(l>>4)*8+j][tap], j=0..7
// (A-operand layout for mfma_f32_16x16x32: A[m=lane&15][k=quad*8+j]).
extern "C" __global__ void prep_kernel(
    const float* w0, const float* w1, const float* w2, const float* w3,
    const float* b0, const float* g0, const float* bb0, const float* rm0, const float* rv0,
    const float* b1, const float* g1, const float* bb1, const float* rm1, const float* rv1,
    const float* b2, const float* g2, const float* bb2, const float* rm2, const float* rv2,
    const float* b3, const float* g3, const float* bb3, const float* rm3, const float* rv3,
    const float* fw1, _Float16* ws)
{
    const int tid  = threadIdx.x;
    const int rec  = blockIdx.x;
    if (rec < NREC) {
        if (tid < 64) {
            const int lane = tid;
            const float* W; int CIN, K, r2;
            if      (rec < 6)  { W = w0;  CIN = 4;  K = 3; r2 = rec;      }
            else if (rec < 12) { W = w1;  CIN = 32; K = 3; r2 = rec - 6;  }
            else if (rec < 22) { W = w2;  CIN = 32; K = 5; r2 = rec - 12; }
            else if (rec < 36) { W = w3;  CIN = 32; K = 7; r2 = rec - 22; }
            else               { W = fw1; CIN = 32; K = 1; r2 = 0;        }
            int tap = r2 >> 1, mh = r2 & 1;
            int co  = mh*16 + (lane & 15);
            int ci0 = (lane >> 4) * 8;
            half8 h;
#pragma unroll
            for (int j = 0; j < 8; ++j) {
                int ci = ci0 + j;
                h[j] = (_Float16)((ci < CIN) ? W[(co*CIN + ci)*K + tap] : 0.0f);
            }
            *(half8*)(ws + rec*512 + lane*8) = h;
        }
    } else if (tid < 128) {
        // Folded BN per (layer, co): x=scale=g/sqrt(rv+eps), y=shift=bb-rm*scale, z=bias.
        int l = tid >> 5, co = tid & 31;
        const float *g, *bb, *rm, *rv, *bi;
        if      (l == 0) { g=g0; bb=bb0; rm=rm0; rv=rv0; bi=b0; }
        else if (l == 1) { g=g1; bb=bb1; rm=rm1; rv=rv1; bi=b1; }
        else if (l == 2) { g=g2; bb=bb2; rm=rm2; rv=rv2; bi=b2; }
        else             { g=g3; bb=bb3; rm=rm3; rv=rv3; bi=b3; }
        float scale = g[co] / sqrtf(rv[co] + 1e-5f);
        float shift = bb[co] - rm[co]*scale;
        float* bn = (float*)(ws + BN_HALFOFF) + (l*32 + co)*4;
        bn[0] = scale; bn[1] = shift; bn[2] = bi[co]; bn[3] = 0.0f;
    }
}

// ---------------- one conv layer via MFMA ----------------
// in/out: LDS f16, 4 chunks x NROW pos x 8 halves (chunk cb holds ci 8cb..8cb+7).
// B-frag (lane l): pos = base+(l&15)+tap, ci = (l>>4)*8+j -> one b128 at q*CS + pos*8.
// D (C/D layout): col=lane&15 -> pos, row=q*4+r -> co (within m-half).
// Wave owns 4 n-tiles: each A-record load feeds 4 MFMAs (halved A traffic, 8
// independent acc chains of ILP). No manual pipelining — R4/R6 showed the
// compiler schedules this structure better than hand-hoisting.
// DOFF: global pos of local 0 = s0+DOFF; outside [0,SEQ) forced to 0 (ref zero-pads).
template<int K, int DOFF>
__device__ __forceinline__ void conv_layer(
    const _Float16* __restrict__ rec, const float4* __restrict__ bn,
    const _Float16* in, _Float16* outb, int s0, int ntb, int lane)
{
    const int q = lane >> 4, n = lane & 15;
    const _Float16* bbase = in + q*CS + (ntb*16 + n)*8;

    f32x4 acc[4][2];
#pragma unroll
    for (int nt = 0; nt < 4; ++nt)
#pragma unroll
        for (int mh = 0; mh < 2; ++mh) acc[nt][mh] = (f32x4){0.f, 0.f, 0.f, 0.f};

#pragma unroll
    for (int tap = 0; tap < K; ++tap) {
        half8 a0 = *(const half8*)(rec + (tap*2 + 0)*512 + lane*8);
        half8 a1 = *(const half8*)(rec + (tap*2 + 1)*512 + lane*8);
#pragma unroll
        for (int nt = 0; nt < 4; ++nt) {
            half8 bf = *(const half8*)(bbase + nt*128 + tap*8);
            acc[nt][0] = __builtin_amdgcn_mfma_f32_16x16x32_f16(a0, bf, acc[nt][0], 0, 0, 0);
            acc[nt][1] = __builtin_amdgcn_mfma_f32_16x16x32_f16(a1, bf, acc[nt][1], 0, 0, 0);
        }
    }

    // epilogue: relu(acc+bias)*scale+shift, seq-edge zero, pack 4 co -> one b64 LDS write
#pragma unroll
    for (int nt = 0; nt < 4; ++nt) {
        int pos = (ntb + nt)*16 + n;
        bool oob = (unsigned)(s0 + DOFF + pos) >= SEQ;
#pragma unroll
        for (int mh = 0; mh < 2; ++mh) {
            int co0 = mh*16 + q*4;
            half4v hv;
#pragma unroll
            for (int r = 0; r < 4; ++r) {
                float4 p = bn[co0 + r];   // x=scale y=shift z=bias
                float v = fmaxf(acc[nt][mh][r] + p.z, 0.0f)*p.x + p.y;
                if (oob) v = 0.0f;
                hv[r] = (_Float16)v;
            }
            int cb = mh*2 + (q >> 1);
            *(half4v*)(outb + cb*CS + pos*8 + (q & 1)*4) = hv;
        }
    }
}

extern "C" __global__ void __launch_bounds__(NTHR, 4)
dnashape_mfma(const float* __restrict__ x, const _Float16* __restrict__ ws,
              const float* __restrict__ fb1, const float* __restrict__ fw2,
              const float* __restrict__ fb2, float* __restrict__ out)
{
    __shared__ _Float16 bufA[4*CS];
    __shared__ _Float16 bufB[4*CS];     // total 33.9 KB -> 4 blocks/CU (1024 thr)

    const int tid  = threadIdx.x;
    const int tile = blockIdx.x, b = blockIdx.y;
    const int s0   = tile * S_TILE;

    // Stage input into bufB: chunk0 = f16(x[ci 0..3]) + 4 zeros, chunks 1-3 zero.
    const half8 z8 = {0,0,0,0,0,0,0,0};
    for (int li = tid; li < NROW; li += NTHR) {
        int sg = s0 - 7 + li;   // input origin s0-7 (halo 7)
        bool ok = (unsigned)sg < SEQ;
        float v0 = ok ? x[(b*4 + 0)*SEQ + sg] : 0.f;
        float v1 = ok ? x[(b*4 + 1)*SEQ + sg] : 0.f;
        float v2 = ok ? x[(b*4 + 2)*SEQ + sg] : 0.f;
        float v3 = ok ? x[(b*4 + 3)*SEQ + sg] : 0.f;
        half8 h0 = {(_Float16)v0, (_Float16)v1, (_Float16)v2, (_Float16)v3, 0, 0, 0, 0};
        *(half8*)(bufB + 0*CS + li*8) = h0;
        *(half8*)(bufB + 1*CS + li*8) = z8;
        *(half8*)(bufB + 2*CS + li*8) = z8;
        *(half8*)(bufB + 3*CS + li*8) = z8;
    }
    // Zero bufA halo rows 256..263 (read by later layers, written by none).
    if (tid < 32) *(half8*)(bufA + (tid >> 3)*CS + (256 + (tid & 7))*8) = z8;
    __syncthreads();

    const int lane = tid & 63;
    const int ntb  = uni(tid >> 6) * 4;     // wave-uniform n-tile base (4 waves x 4 nt)
    const float4* bn = (const float4*)(ws + BN_HALFOFF);

    // Buffer origins: in=s0-7, L0out=s0-6, L1out=s0-5, L2out=s0-3, L3out=s0.
    conv_layer<3, -6>(ws +  0*512, bn +  0, bufB, bufA, s0, ntb, lane);
    __syncthreads();
    conv_layer<3, -5>(ws +  6*512, bn + 32, bufA, bufB, s0, ntb, lane);
    __syncthreads();
    conv_layer<5, -3>(ws + 12*512, bn + 64, bufB, bufA, s0, ntb, lane);
    __syncthreads();
    conv_layer<7,  0>(ws + 22*512, bn + 96, bufA, bufB, s0, ntb, lane);
    __syncthreads();

    // MLP 32 -> 16 (relu) -> 1: one MFMA per n-tile; D row = h, col = pos.
    {
        const int q = lane >> 4, n = lane & 15;
        half8 am = *(const half8*)(ws + 36*512 + lane*8);
        float fb1v[4], fw2v[4];
#pragma unroll
        for (int r = 0; r < 4; ++r) { fb1v[r] = fb1[q*4 + r]; fw2v[r] = fw2[q*4 + r]; }
        float fb2v = fb2[0];
#pragma unroll
        for (int nt = 0; nt < 4; ++nt) {
            int pos = (ntb + nt)*16 + n;
            half8 bf = *(const half8*)(bufB + q*CS + pos*8);
            f32x4 d = {0.f, 0.f, 0.f, 0.f};
            d = __builtin_amdgcn_mfma_f32_16x16x32_f16(am, bf, d, 0, 0, 0);
            float part = 0.f;
#pragma unroll
            for (int r = 0; r < 4; ++r) part += fmaxf(d[r] + fb1v[r], 0.f)*fw2v[r];
            part += __shfl_xor(part, 16, 64);   // reduce across the 4 quads (h-blocks)
            part += __shfl_xor(part, 32, 64);
            if (lane < 16) {
                int g = s0 + pos;
                if (pos < S_TILE && g < SEQ) out[b*SEQ + g] = part + fb2v;
            }
        }
    }
}

extern "C" void kernel_launch(void* const* d_in, const int* in_sizes, int n_in,
                              void* d_out, int out_size, void* d_ws, size_t ws_size,
                              hipStream_t stream) {
    const float* p[29];
    for (int i = 0; i < 29; ++i) p[i] = (const float*)d_in[i];
    _Float16* ws = (_Float16*)d_ws;   // needs 37*1024 + 2048 = 39936 B

    prep_kernel<<<dim3(NREC + 1), 128, 0, stream>>>(
        p[1], p[7], p[13], p[19],
        p[2], p[3], p[4], p[5], p[6],
        p[8], p[9], p[10], p[11], p[12],
        p[14], p[15], p[16], p[17], p[18],
        p[20], p[21], p[22], p[23], p[24],
        p[25], ws);

    dim3 grid((SEQ + S_TILE - 1) / S_TILE, 128);   // 34 x 128
    dnashape_mfma<<<grid, NTHR, 0, stream>>>(p[0], (const _Float16*)ws,
                                             p[26], p[27], p[28], (float*)d_out);
}